// Round 3
// baseline (745.976 us; speedup 1.0000x reference)
//
#include <hip/hip_runtime.h>
#include <hip/hip_bf16.h>
#include <cstdint>

#define S_LEN 2048
#define B_SZ  32
#define H_DIM 1024
#define U_DIM 1024

#define BM 128
#define BN 128
#define BK 64    // v3: 16 K-iters, 32 MFMA per barrier-pair

using short8  = __attribute__((ext_vector_type(8))) short;
using floatx4 = __attribute__((ext_vector_type(4))) float;

typedef __attribute__((address_space(3))) void lds_void;
typedef const __attribute__((address_space(1))) void glb_void;
#define GLD16(g, s) __builtin_amdgcn_global_load_lds((glb_void*)(g), (lds_void*)(s), 16, 0, 0)

__device__ __forceinline__ unsigned short f32_to_bf16_rne(float f) {
    unsigned int u = __float_as_uint(f);
    unsigned int r = (u + 0x7fffu + ((u >> 16) & 1u)) >> 16;
    return (unsigned short)r;
}

// ---------------- hiddens f32 -> bf16 (8 elems/thread, 16B store) ----------------
__global__ __launch_bounds__(256)
void cast_hiddens_kernel(const float* __restrict__ src, unsigned short* __restrict__ dst) {
    const size_t i = ((size_t)blockIdx.x * 256 + threadIdx.x) * 8;
    float4 a = *(const float4*)(src + i);
    float4 b = *(const float4*)(src + i + 4);
    ushort4 lo, hi;
    lo.x = f32_to_bf16_rne(a.x); lo.y = f32_to_bf16_rne(a.y);
    lo.z = f32_to_bf16_rne(a.z); lo.w = f32_to_bf16_rne(a.w);
    hi.x = f32_to_bf16_rne(b.x); hi.y = f32_to_bf16_rne(b.y);
    hi.z = f32_to_bf16_rne(b.z); hi.w = f32_to_bf16_rne(b.w);
    *(ushort4*)(dst + i)     = lo;
    *(ushort4*)(dst + i + 4) = hi;
}

// ---------------- W1 [H][U] f32 -> W1t [U][H] bf16 ----------------
__global__ void transpose_cast_w1(const float* __restrict__ W1,
                                  unsigned short* __restrict__ W1t) {
    __shared__ float tile[32][33];
    const int tx = threadIdx.x, ty = threadIdx.y;      // 32 x 8
    const int u0 = blockIdx.x * 32, h0 = blockIdx.y * 32;
#pragma unroll
    for (int i = 0; i < 4; ++i)
        tile[ty * 4 + i][tx] = W1[(size_t)(h0 + ty * 4 + i) * U_DIM + u0 + tx];
    __syncthreads();
#pragma unroll
    for (int i = 0; i < 4; ++i)
        W1t[(size_t)(u0 + ty * 4 + i) * H_DIM + h0 + tx] =
            f32_to_bf16_rne(tile[tx][ty * 4 + i]);
}

// ---------------- query[b][u] = hidden_t[b]·W2[:,u] + b1[u] + b2[u] ----------------
__global__ void query_kernel(const float* __restrict__ hidden_t,
                             const float* __restrict__ W2,
                             const float* __restrict__ b1,
                             const float* __restrict__ b2,
                             float* __restrict__ query) {
    const int b = blockIdx.y;
    const int u = blockIdx.x * 128 + threadIdx.x;
    const float* ht = hidden_t + b * H_DIM;
    float acc = b1[u] + b2[u];
#pragma unroll 8
    for (int h = 0; h < H_DIM; ++h)
        acc = fmaf(ht[h], W2[(size_t)h * U_DIM + u], acc);
    query[b * U_DIM + u] = acc;
}

// ---------------- epilogue helper: tanh(c+q)·V, 16-lane reduce, atomic ----------------
__device__ __forceinline__ void score_epilogue(const floatx4 acc[4][4],
                                               const float* __restrict__ qrow,
                                               const float* __restrict__ V,
                                               float* __restrict__ scores,
                                               int m0, int n0, int wr, int wc, int q, int r) {
#pragma unroll
    for (int mt = 0; mt < 4; ++mt) {
#pragma unroll
        for (int reg = 0; reg < 4; ++reg) {
            float sum = 0.f;
#pragma unroll
            for (int nt = 0; nt < 4; ++nt) {
                const int c = n0 + wc * 64 + nt * 16 + r;
                float x = acc[mt][nt][reg] + qrow[c];
                x = fminf(fmaxf(x, -15.f), 15.f);
                float e = __expf(2.f * x);
                float t = (e - 1.f) / (e + 1.f);
                sum = fmaf(t, V[c], sum);
            }
            sum += __shfl_xor(sum, 1);
            sum += __shfl_xor(sum, 2);
            sum += __shfl_xor(sum, 4);
            sum += __shfl_xor(sum, 8);
            if (r == 0)
                atomicAdd(&scores[m0 + wr * 64 + mt * 16 + q * 4 + reg], sum);
        }
    }
}

// ---------------- v3: BK=64, XCD-swizzled grid, global_load_lds staging ----------------
__global__ __launch_bounds__(256)
void keys_score_v3(const unsigned short* __restrict__ hb,
                   const unsigned short* __restrict__ W1t,
                   const float* __restrict__ query,
                   const float* __restrict__ V,
                   float* __restrict__ scores) {
    __shared__ unsigned short As[BM * BK];   // 16 KB
    __shared__ unsigned short Bs[BN * BK];   // 16 KB

    const int tid = threadIdx.x;
    const int w = tid >> 6, l = tid & 63;
    const int q = l >> 4, r = l & 15;
    const int wr = w >> 1, wc = w & 1;

    // XCD swizzle: with round-robin bid->XCD, put the 8 col-siblings of a
    // row-band dispatch-consecutive on ONE XCD so A re-reads hit its L2.
    const int bid = blockIdx.x;
    const int col      = (bid >> 3) & 7;
    const int row_band = ((bid >> 6) << 3) | (bid & 7);
    const int m0 = row_band * BM;
    const int n0 = col * BN;

    // staging: lane l covers (row l>>3, 16B chunk l&7) of a 32-row slab; 4 slabs
    const int srow   = l >> 3;
    const int schunk = (l & 7) * 8;

    const unsigned short* gA = hb  + ((size_t)(m0 + w * 8 + srow) << 10) + schunk;
    const unsigned short* gB = W1t + ((size_t)(n0 + w * 8 + srow) << 10) + schunk;
    unsigned short* lA = &As[(w * 8) * BK];
    unsigned short* lB = &Bs[(w * 8) * BK];

    floatx4 acc[4][4];
#pragma unroll
    for (int mt = 0; mt < 4; ++mt)
#pragma unroll
        for (int nt = 0; nt < 4; ++nt)
            acc[mt][nt] = (floatx4){0.f, 0.f, 0.f, 0.f};

    for (int kt = 0; kt < H_DIM / BK; ++kt) {
#pragma unroll
        for (int i = 0; i < 4; ++i) {
            GLD16(gA + ((size_t)(i * 32) << 10), lA + i * 32 * BK);
            GLD16(gB + ((size_t)(i * 32) << 10), lB + i * 32 * BK);
        }
        gA += BK; gB += BK;

        __syncthreads();

#pragma unroll
        for (int kh = 0; kh < 2; ++kh) {
            short8 af[4], bfr[4];
#pragma unroll
            for (int mt = 0; mt < 4; ++mt)
                af[mt] = *(const short8*)&As[(wr * 64 + mt * 16 + r) * BK + kh * 32 + q * 8];
#pragma unroll
            for (int nt = 0; nt < 4; ++nt)
                bfr[nt] = *(const short8*)&Bs[(wc * 64 + nt * 16 + r) * BK + kh * 32 + q * 8];
#pragma unroll
            for (int mt = 0; mt < 4; ++mt)
#pragma unroll
                for (int nt = 0; nt < 4; ++nt)
                    acc[mt][nt] = __builtin_amdgcn_mfma_f32_16x16x32_bf16(
                        af[mt], bfr[nt], acc[mt][nt], 0, 0, 0);
        }

        __syncthreads();
    }

    const float* qrow = query + (m0 >> 11) * U_DIM;
    score_epilogue(acc, qrow, V, scores, m0, n0, wr, wc, q, r);
}

// ---------------- v1 fallback (f32 hiddens staged via VGPR) ----------------
__global__ __launch_bounds__(256)
void keys_score_v1(const float* __restrict__ hiddens,
                   const unsigned short* __restrict__ W1t,
                   const float* __restrict__ query,
                   const float* __restrict__ V,
                   float* __restrict__ scores) {
    __shared__ unsigned short As[BM][40];
    __shared__ unsigned short Bs[BN][40];
    const int tid = threadIdx.x;
    const int lane = tid & 63, wave = tid >> 6;
    const int q = lane >> 4, r = lane & 15;
    const int wr = wave >> 1, wc = wave & 1;
    const int m0 = blockIdx.y * BM, n0 = blockIdx.x * BN;
    const int arow = tid >> 3, achunk = tid & 7;
    const int brow = tid >> 2, bchunk = tid & 3;
    floatx4 acc[4][4];
#pragma unroll
    for (int mt = 0; mt < 4; ++mt)
#pragma unroll
        for (int nt = 0; nt < 4; ++nt)
            acc[mt][nt] = (floatx4){0.f, 0.f, 0.f, 0.f};
    for (int kt = 0; kt < H_DIM / 32; ++kt) {
        const float* ag = hiddens + (size_t)(m0 + arow) * H_DIM + kt * 32 + achunk * 4;
#pragma unroll
        for (int i = 0; i < 4; ++i) {
            float4 f = *(const float4*)(ag + (size_t)i * 32 * H_DIM);
            ushort4 h;
            h.x = f32_to_bf16_rne(f.x); h.y = f32_to_bf16_rne(f.y);
            h.z = f32_to_bf16_rne(f.z); h.w = f32_to_bf16_rne(f.w);
            *(ushort4*)&As[arow + i * 32][achunk * 4] = h;
        }
        const unsigned short* bg = W1t + (size_t)(n0 + brow) * H_DIM + kt * 32 + bchunk * 8;
#pragma unroll
        for (int i = 0; i < 2; ++i)
            *(uint4*)&Bs[brow + i * 64][bchunk * 8] = *(const uint4*)(bg + (size_t)i * 64 * H_DIM);
        __syncthreads();
        short8 af[4], bfr[4];
#pragma unroll
        for (int mt = 0; mt < 4; ++mt)
            af[mt] = *(const short8*)&As[wr * 64 + mt * 16 + r][q * 8];
#pragma unroll
        for (int nt = 0; nt < 4; ++nt)
            bfr[nt] = *(const short8*)&Bs[wc * 64 + nt * 16 + r][q * 8];
#pragma unroll
        for (int mt = 0; mt < 4; ++mt)
#pragma unroll
            for (int nt = 0; nt < 4; ++nt)
                acc[mt][nt] = __builtin_amdgcn_mfma_f32_16x16x32_bf16(
                    af[mt], bfr[nt], acc[mt][nt], 0, 0, 0);
        __syncthreads();
    }
    const float* qrow = query + (m0 >> 11) * U_DIM;
    score_epilogue(acc, qrow, V, scores, m0, n0, wr, wc, q, r);
}

// ---------------- softmax over S per batch ----------------
__global__ void softmax_kernel(const float* __restrict__ scores,
                               float* __restrict__ wout) {
    const int b = blockIdx.x, tid = threadIdx.x;
    const int wave = tid >> 6, lane = tid & 63;
    const float* src = scores + b * S_LEN;
    float v[8];
    float m = -1e30f;
#pragma unroll
    for (int i = 0; i < 8; ++i) { v[i] = src[tid + i * 256]; m = fmaxf(m, v[i]); }
#pragma unroll
    for (int off = 32; off >= 1; off >>= 1) m = fmaxf(m, __shfl_xor(m, off));
    __shared__ float red[4];
    if (lane == 0) red[wave] = m;
    __syncthreads();
    m = fmaxf(fmaxf(red[0], red[1]), fmaxf(red[2], red[3]));
    __syncthreads();
    float s = 0.f;
#pragma unroll
    for (int i = 0; i < 8; ++i) { v[i] = __expf(v[i] - m); s += v[i]; }
#pragma unroll
    for (int off = 32; off >= 1; off >>= 1) s += __shfl_xor(s, off);
    if (lane == 0) red[wave] = s;
    __syncthreads();
    s = red[0] + red[1] + red[2] + red[3];
    const float inv = 1.f / s;
#pragma unroll
    for (int i = 0; i < 8; ++i) wout[b * S_LEN + tid + i * 256] = v[i] * inv;
}

// ---------------- context[b][h] = sum_s w[b][s] * hiddens[b][s][h] ----------------
__global__ __launch_bounds__(256)
void context_kernel(const float* __restrict__ weights,
                    const float* __restrict__ hiddens,
                    float* __restrict__ out_ctx) {
    const int b = blockIdx.y;
    const int sc = blockIdx.x;  // chunk of 64 s
    const int h4 = threadIdx.x * 4;
    const float* wrow = weights + b * S_LEN + sc * 64;
    const float* hbase = hiddens + ((size_t)b * S_LEN + sc * 64) * H_DIM + h4;
    float4 acc = make_float4(0.f, 0.f, 0.f, 0.f);
    for (int s = 0; s < 64; ++s) {
        const float w = wrow[s];
        float4 hv = *(const float4*)(hbase + (size_t)s * H_DIM);
        acc.x = fmaf(w, hv.x, acc.x);
        acc.y = fmaf(w, hv.y, acc.y);
        acc.z = fmaf(w, hv.z, acc.z);
        acc.w = fmaf(w, hv.w, acc.w);
    }
    float* o = out_ctx + b * H_DIM + h4;
    atomicAdd(o + 0, acc.x);
    atomicAdd(o + 1, acc.y);
    atomicAdd(o + 2, acc.z);
    atomicAdd(o + 3, acc.w);
}

extern "C" void kernel_launch(void* const* d_in, const int* in_sizes, int n_in,
                              void* d_out, int out_size, void* d_ws, size_t ws_size,
                              hipStream_t stream) {
    const float* hidden_t = (const float*)d_in[0];
    const float* hiddens  = (const float*)d_in[1];
    const float* W1       = (const float*)d_in[2];
    const float* b1       = (const float*)d_in[3];
    const float* W2       = (const float*)d_in[4];
    const float* b2       = (const float*)d_in[5];
    const float* V        = (const float*)d_in[6];
    // d_in[7] = bV: softmax-invariant, unused.

    float* out_ctx = (float*)d_out;                  // [32,1024]
    float* out_w   = (float*)d_out + B_SZ * H_DIM;   // [32,2048,1]

    char* ws = (char*)d_ws;
    unsigned short* W1t = (unsigned short*)ws;                        // 2 MiB @ 0
    float* query  = (float*)(ws + (2u << 20));                        // 128 KiB
    float* scores = query + B_SZ * U_DIM;                             // 256 KiB
    unsigned short* hb = (unsigned short*)(ws + (4u << 20));          // 128 MiB @ 4 MiB
    const size_t need = (4u << 20) + (size_t)B_SZ * S_LEN * H_DIM * 2;

    hipMemsetAsync(scores, 0, (size_t)B_SZ * S_LEN * sizeof(float), stream);
    hipMemsetAsync(out_ctx, 0, (size_t)B_SZ * H_DIM * sizeof(float), stream);

    transpose_cast_w1<<<dim3(32, 32), dim3(32, 8), 0, stream>>>(W1, W1t);
    query_kernel<<<dim3(8, B_SZ), 128, 0, stream>>>(hidden_t, W2, b1, b2, query);

    if (ws_size >= need) {
        cast_hiddens_kernel<<<32768, 256, 0, stream>>>(hiddens, hb);
        keys_score_v3<<<(U_DIM / BN) * ((B_SZ * S_LEN) / BM), 256, 0, stream>>>(
            hb, W1t, query, V, scores);
    } else {
        keys_score_v1<<<dim3(U_DIM / 128, (B_SZ * S_LEN) / BM), 256, 0, stream>>>(
            hiddens, W1t, query, V, scores);
    }

    softmax_kernel<<<B_SZ, 256, 0, stream>>>(scores, out_w);
    context_kernel<<<dim3(S_LEN / 64, B_SZ), 256, 0, stream>>>(out_w, hiddens, out_ctx);
}

// Round 4
// 660.730 us; speedup vs baseline: 1.1290x; 1.1290x over previous
//
#include <hip/hip_runtime.h>
#include <hip/hip_bf16.h>
#include <cstdint>

#define S_LEN 2048
#define B_SZ  32
#define H_DIM 1024
#define U_DIM 1024

#define BM 128
#define BN 128
#define BK 64

using short8  = __attribute__((ext_vector_type(8))) short;
using floatx4 = __attribute__((ext_vector_type(4))) float;

typedef __attribute__((address_space(3))) void lds_void;
typedef const __attribute__((address_space(1))) void glb_void;
#define GLD16(g, s) __builtin_amdgcn_global_load_lds((glb_void*)(g), (lds_void*)(s), 16, 0, 0)

__device__ __forceinline__ unsigned short f32_to_bf16_rne(float f) {
    unsigned int u = __float_as_uint(f);
    unsigned int r = (u + 0x7fffu + ((u >> 16) & 1u)) >> 16;
    return (unsigned short)r;
}

// ---------------- hiddens f32 -> bf16 ----------------
__global__ __launch_bounds__(256)
void cast_hiddens_kernel(const float* __restrict__ src, unsigned short* __restrict__ dst) {
    const size_t i = ((size_t)blockIdx.x * 256 + threadIdx.x) * 8;
    float4 a = *(const float4*)(src + i);
    float4 b = *(const float4*)(src + i + 4);
    ushort4 lo, hi;
    lo.x = f32_to_bf16_rne(a.x); lo.y = f32_to_bf16_rne(a.y);
    lo.z = f32_to_bf16_rne(a.z); lo.w = f32_to_bf16_rne(a.w);
    hi.x = f32_to_bf16_rne(b.x); hi.y = f32_to_bf16_rne(b.y);
    hi.z = f32_to_bf16_rne(b.z); hi.w = f32_to_bf16_rne(b.w);
    *(ushort4*)(dst + i)     = lo;
    *(ushort4*)(dst + i + 4) = hi;
}

// ---------------- W1 [H][U] f32 -> W1t [U][H] bf16 ----------------
__global__ void transpose_cast_w1(const float* __restrict__ W1,
                                  unsigned short* __restrict__ W1t) {
    __shared__ float tile[32][33];
    const int tx = threadIdx.x, ty = threadIdx.y;      // 32 x 8
    const int u0 = blockIdx.x * 32, h0 = blockIdx.y * 32;
#pragma unroll
    for (int i = 0; i < 4; ++i)
        tile[ty * 4 + i][tx] = W1[(size_t)(h0 + ty * 4 + i) * U_DIM + u0 + tx];
    __syncthreads();
#pragma unroll
    for (int i = 0; i < 4; ++i)
        W1t[(size_t)(u0 + ty * 4 + i) * H_DIM + h0 + tx] =
            f32_to_bf16_rne(tile[tx][ty * 4 + i]);
}

// ---------------- query v2: split-H partial sums + atomics ----------------
__global__ __launch_bounds__(128)
void query_kernel_v2(const float* __restrict__ hidden_t,
                     const float* __restrict__ W2,
                     const float* __restrict__ b1,
                     const float* __restrict__ b2,
                     float* __restrict__ query) {
    const int b  = blockIdx.z;
    const int hc = blockIdx.y;                 // 8 chunks of 128 h
    const int u  = blockIdx.x * 128 + threadIdx.x;
    const float* ht = hidden_t + b * H_DIM + hc * 128;
    const float* w  = W2 + (size_t)hc * 128 * U_DIM + u;
    float acc = (hc == 0) ? (b1[u] + b2[u]) : 0.f;
#pragma unroll 8
    for (int h = 0; h < 128; ++h)
        acc = fmaf(ht[h], w[(size_t)h * U_DIM], acc);
    atomicAdd(&query[b * U_DIM + u], acc);
}

// ---------------- epilogue: tanh(c+q)·V, 16-lane reduce, atomic ----------------
__device__ __forceinline__ void score_epilogue(const floatx4 acc[4][4],
                                               const float* __restrict__ qrow,
                                               const float* __restrict__ V,
                                               float* __restrict__ scores,
                                               int m0, int n0, int wr, int wc, int q, int r) {
#pragma unroll
    for (int mt = 0; mt < 4; ++mt) {
#pragma unroll
        for (int reg = 0; reg < 4; ++reg) {
            float sum = 0.f;
#pragma unroll
            for (int nt = 0; nt < 4; ++nt) {
                const int c = n0 + wc * 64 + nt * 16 + r;
                float x = acc[mt][nt][reg] + qrow[c];
                x = fminf(fmaxf(x, -15.f), 15.f);
                float e = __expf(2.f * x);
                float t = (e - 1.f) / (e + 1.f);
                sum = fmaf(t, V[c], sum);
            }
            sum += __shfl_xor(sum, 1);
            sum += __shfl_xor(sum, 2);
            sum += __shfl_xor(sum, 4);
            sum += __shfl_xor(sum, 8);
            if (r == 0)
                atomicAdd(&scores[m0 + wr * 64 + mt * 16 + q * 4 + reg], sum);
        }
    }
}

// ---------------- v4: BK=64 + XOR bank swizzle + XCD grid swizzle ----------------
// LDS layout: chunk c (16B) of row R holds GLOBAL chunk c ^ (R&7).
// Staging lane l -> LDS (row base+l>>3, chunk l&7) loads global chunk (l&7)^(l>>3).
// Readers address chunk (c ^ (R&7)); bank-quad = (c^R)&7 -> uniform, conflict-free.
__global__ __launch_bounds__(256)
void keys_score_v4(const unsigned short* __restrict__ hb,
                   const unsigned short* __restrict__ W1t,
                   const float* __restrict__ query,
                   const float* __restrict__ V,
                   float* __restrict__ scores) {
    __shared__ unsigned short As[BM * BK];   // 16 KB
    __shared__ unsigned short Bs[BN * BK];   // 16 KB

    const int tid = threadIdx.x;
    const int w = tid >> 6, l = tid & 63;
    const int q = l >> 4, r = l & 15;
    const int wr = w >> 1, wc = w & 1;

    // XCD swizzle: 8 col-siblings of one row-band dispatch-consecutive.
    const int bid = blockIdx.x;
    const int col      = (bid >> 3) & 7;
    const int row_band = ((bid >> 6) << 3) | (bid & 7);
    const int m0 = row_band * BM;
    const int n0 = col * BN;

    const int srow   = l >> 3;                    // 0..7
    const int gchunk = ((l & 7) ^ srow) * 8;      // swizzled global chunk (bf16 elems)

    const unsigned short* gA = hb  + ((size_t)(m0 + w * 8 + srow) << 10) + gchunk;
    const unsigned short* gB = W1t + ((size_t)(n0 + w * 8 + srow) << 10) + gchunk;
    unsigned short* lA = &As[(w * 8) * BK];
    unsigned short* lB = &Bs[(w * 8) * BK];

    floatx4 acc[4][4];
#pragma unroll
    for (int mt = 0; mt < 4; ++mt)
#pragma unroll
        for (int nt = 0; nt < 4; ++nt)
            acc[mt][nt] = (floatx4){0.f, 0.f, 0.f, 0.f};

    const int r7 = r & 7;
    for (int kt = 0; kt < H_DIM / BK; ++kt) {
#pragma unroll
        for (int i = 0; i < 4; ++i) {
            GLD16(gA + ((size_t)(i * 32) << 10), lA + i * 32 * BK);
            GLD16(gB + ((size_t)(i * 32) << 10), lB + i * 32 * BK);
        }
        gA += BK; gB += BK;

        __syncthreads();

#pragma unroll
        for (int kh = 0; kh < 2; ++kh) {
            short8 af[4], bfr[4];
#pragma unroll
            for (int mt = 0; mt < 4; ++mt)
                af[mt] = *(const short8*)
                    &As[(wr * 64 + mt * 16 + r) * BK + (((kh << 2) | q) ^ r7) * 8];
#pragma unroll
            for (int nt = 0; nt < 4; ++nt)
                bfr[nt] = *(const short8*)
                    &Bs[(wc * 64 + nt * 16 + r) * BK + (((kh << 2) | q) ^ r7) * 8];
#pragma unroll
            for (int mt = 0; mt < 4; ++mt)
#pragma unroll
                for (int nt = 0; nt < 4; ++nt)
                    acc[mt][nt] = __builtin_amdgcn_mfma_f32_16x16x32_bf16(
                        af[mt], bfr[nt], acc[mt][nt], 0, 0, 0);
        }

        __syncthreads();
    }

    const float* qrow = query + (m0 >> 11) * U_DIM;
    score_epilogue(acc, qrow, V, scores, m0, n0, wr, wc, q, r);
}

// ---------------- v1 fallback (f32 hiddens staged via VGPR) ----------------
__global__ __launch_bounds__(256)
void keys_score_v1(const float* __restrict__ hiddens,
                   const unsigned short* __restrict__ W1t,
                   const float* __restrict__ query,
                   const float* __restrict__ V,
                   float* __restrict__ scores) {
    __shared__ unsigned short As[BM][40];
    __shared__ unsigned short Bs[BN][40];
    const int tid = threadIdx.x;
    const int lane = tid & 63, wave = tid >> 6;
    const int q = lane >> 4, r = lane & 15;
    const int wr = wave >> 1, wc = wave & 1;
    const int m0 = blockIdx.y * BM, n0 = blockIdx.x * BN;
    const int arow = tid >> 3, achunk = tid & 7;
    const int brow = tid >> 2, bchunk = tid & 3;
    floatx4 acc[4][4];
#pragma unroll
    for (int mt = 0; mt < 4; ++mt)
#pragma unroll
        for (int nt = 0; nt < 4; ++nt)
            acc[mt][nt] = (floatx4){0.f, 0.f, 0.f, 0.f};
    for (int kt = 0; kt < H_DIM / 32; ++kt) {
        const float* ag = hiddens + (size_t)(m0 + arow) * H_DIM + kt * 32 + achunk * 4;
#pragma unroll
        for (int i = 0; i < 4; ++i) {
            float4 f = *(const float4*)(ag + (size_t)i * 32 * H_DIM);
            ushort4 h;
            h.x = f32_to_bf16_rne(f.x); h.y = f32_to_bf16_rne(f.y);
            h.z = f32_to_bf16_rne(f.z); h.w = f32_to_bf16_rne(f.w);
            *(ushort4*)&As[arow + i * 32][achunk * 4] = h;
        }
        const unsigned short* bg = W1t + (size_t)(n0 + brow) * H_DIM + kt * 32 + bchunk * 8;
#pragma unroll
        for (int i = 0; i < 2; ++i)
            *(uint4*)&Bs[brow + i * 64][bchunk * 8] = *(const uint4*)(bg + (size_t)i * 64 * H_DIM);
        __syncthreads();
        short8 af[4], bfr[4];
#pragma unroll
        for (int mt = 0; mt < 4; ++mt)
            af[mt] = *(const short8*)&As[wr * 64 + mt * 16 + r][q * 8];
#pragma unroll
        for (int nt = 0; nt < 4; ++nt)
            bfr[nt] = *(const short8*)&Bs[wc * 64 + nt * 16 + r][q * 8];
#pragma unroll
        for (int mt = 0; mt < 4; ++mt)
#pragma unroll
            for (int nt = 0; nt < 4; ++nt)
                acc[mt][nt] = __builtin_amdgcn_mfma_f32_16x16x32_bf16(
                    af[mt], bfr[nt], acc[mt][nt], 0, 0, 0);
        __syncthreads();
    }
    const float* qrow = query + (m0 >> 11) * U_DIM;
    score_epilogue(acc, qrow, V, scores, m0, n0, wr, wc, q, r);
}

// ---------------- softmax over S per batch ----------------
__global__ void softmax_kernel(const float* __restrict__ scores,
                               float* __restrict__ wout) {
    const int b = blockIdx.x, tid = threadIdx.x;
    const int wave = tid >> 6, lane = tid & 63;
    const float* src = scores + b * S_LEN;
    float v[8];
    float m = -1e30f;
#pragma unroll
    for (int i = 0; i < 8; ++i) { v[i] = src[tid + i * 256]; m = fmaxf(m, v[i]); }
#pragma unroll
    for (int off = 32; off >= 1; off >>= 1) m = fmaxf(m, __shfl_xor(m, off));
    __shared__ float red[4];
    if (lane == 0) red[wave] = m;
    __syncthreads();
    m = fmaxf(fmaxf(red[0], red[1]), fmaxf(red[2], red[3]));
    __syncthreads();
    float s = 0.f;
#pragma unroll
    for (int i = 0; i < 8; ++i) { v[i] = __expf(v[i] - m); s += v[i]; }
#pragma unroll
    for (int off = 32; off >= 1; off >>= 1) s += __shfl_xor(s, off);
    if (lane == 0) red[wave] = s;
    __syncthreads();
    s = red[0] + red[1] + red[2] + red[3];
    const float inv = 1.f / s;
#pragma unroll
    for (int i = 0; i < 8; ++i) wout[b * S_LEN + tid + i * 256] = v[i] * inv;
}

// ---------------- context[b][h] = sum_s w[b][s] * hiddens[b][s][h] ----------------
__global__ __launch_bounds__(256)
void context_kernel(const float* __restrict__ weights,
                    const float* __restrict__ hiddens,
                    float* __restrict__ out_ctx) {
    const int b = blockIdx.y;
    const int sc = blockIdx.x;  // chunk of 32 s
    const int h4 = threadIdx.x * 4;
    const float* wrow = weights + b * S_LEN + sc * 32;
    const float* hbase = hiddens + ((size_t)b * S_LEN + sc * 32) * H_DIM + h4;
    float4 acc = make_float4(0.f, 0.f, 0.f, 0.f);
#pragma unroll 4
    for (int s = 0; s < 32; ++s) {
        const float w = wrow[s];
        float4 hv = *(const float4*)(hbase + (size_t)s * H_DIM);
        acc.x = fmaf(w, hv.x, acc.x);
        acc.y = fmaf(w, hv.y, acc.y);
        acc.z = fmaf(w, hv.z, acc.z);
        acc.w = fmaf(w, hv.w, acc.w);
    }
    float* o = out_ctx + b * H_DIM + h4;
    atomicAdd(o + 0, acc.x);
    atomicAdd(o + 1, acc.y);
    atomicAdd(o + 2, acc.z);
    atomicAdd(o + 3, acc.w);
}

extern "C" void kernel_launch(void* const* d_in, const int* in_sizes, int n_in,
                              void* d_out, int out_size, void* d_ws, size_t ws_size,
                              hipStream_t stream) {
    const float* hidden_t = (const float*)d_in[0];
    const float* hiddens  = (const float*)d_in[1];
    const float* W1       = (const float*)d_in[2];
    const float* b1       = (const float*)d_in[3];
    const float* W2       = (const float*)d_in[4];
    const float* b2       = (const float*)d_in[5];
    const float* V        = (const float*)d_in[6];
    // d_in[7] = bV: softmax-invariant, unused.

    float* out_ctx = (float*)d_out;                  // [32,1024]
    float* out_w   = (float*)d_out + B_SZ * H_DIM;   // [32,2048,1]

    char* ws = (char*)d_ws;
    unsigned short* W1t = (unsigned short*)ws;                        // 2 MiB @ 0
    float* query  = (float*)(ws + (2u << 20));                        // 128 KiB
    float* scores = query + B_SZ * U_DIM;                             // 256 KiB
    unsigned short* hb = (unsigned short*)(ws + (4u << 20));          // 128 MiB @ 4 MiB
    const size_t need = (4u << 20) + (size_t)B_SZ * S_LEN * H_DIM * 2;

    hipMemsetAsync(query,  0, (size_t)B_SZ * U_DIM * sizeof(float), stream);
    hipMemsetAsync(scores, 0, (size_t)B_SZ * S_LEN * sizeof(float), stream);
    hipMemsetAsync(out_ctx, 0, (size_t)B_SZ * H_DIM * sizeof(float), stream);

    transpose_cast_w1<<<dim3(32, 32), dim3(32, 8), 0, stream>>>(W1, W1t);
    query_kernel_v2<<<dim3(8, 8, B_SZ), 128, 0, stream>>>(hidden_t, W2, b1, b2, query);

    if (ws_size >= need) {
        cast_hiddens_kernel<<<32768, 256, 0, stream>>>(hiddens, hb);
        keys_score_v4<<<(U_DIM / BN) * ((B_SZ * S_LEN) / BM), 256, 0, stream>>>(
            hb, W1t, query, V, scores);
    } else {
        keys_score_v1<<<dim3(U_DIM / 128, (B_SZ * S_LEN) / BM), 256, 0, stream>>>(
            hiddens, W1t, query, V, scores);
    }

    softmax_kernel<<<B_SZ, 256, 0, stream>>>(scores, out_w);
    context_kernel<<<dim3(S_LEN / 32, B_SZ), 256, 0, stream>>>(out_w, hiddens, out_ctx);
}

// Round 5
// 648.092 us; speedup vs baseline: 1.1510x; 1.0195x over previous
//
#include <hip/hip_runtime.h>
#include <hip/hip_bf16.h>
#include <cstdint>

#define S_LEN 2048
#define B_SZ  32
#define H_DIM 1024
#define U_DIM 1024

#define BM 128
#define BN 128
#define BK 64

using short8  = __attribute__((ext_vector_type(8))) short;
using floatx4 = __attribute__((ext_vector_type(4))) float;

typedef __attribute__((address_space(3))) void lds_void;
typedef const __attribute__((address_space(1))) void glb_void;
#define GLD16(g, s) __builtin_amdgcn_global_load_lds((glb_void*)(g), (lds_void*)(s), 16, 0, 0)

__device__ __forceinline__ unsigned short f32_to_bf16_rne(float f) {
    unsigned int u = __float_as_uint(f);
    unsigned int r = (u + 0x7fffu + ((u >> 16) & 1u)) >> 16;
    return (unsigned short)r;
}

// ---------------- hiddens f32 -> bf16 ----------------
__global__ __launch_bounds__(256)
void cast_hiddens_kernel(const float* __restrict__ src, unsigned short* __restrict__ dst) {
    const size_t i = ((size_t)blockIdx.x * 256 + threadIdx.x) * 8;
    float4 a = *(const float4*)(src + i);
    float4 b = *(const float4*)(src + i + 4);
    ushort4 lo, hi;
    lo.x = f32_to_bf16_rne(a.x); lo.y = f32_to_bf16_rne(a.y);
    lo.z = f32_to_bf16_rne(a.z); lo.w = f32_to_bf16_rne(a.w);
    hi.x = f32_to_bf16_rne(b.x); hi.y = f32_to_bf16_rne(b.y);
    hi.z = f32_to_bf16_rne(b.z); hi.w = f32_to_bf16_rne(b.w);
    *(ushort4*)(dst + i)     = lo;
    *(ushort4*)(dst + i + 4) = hi;
}

// ---------------- W1 [H][U] f32 -> W1t [U][H] bf16 ----------------
__global__ void transpose_cast_w1(const float* __restrict__ W1,
                                  unsigned short* __restrict__ W1t) {
    __shared__ float tile[32][33];
    const int tx = threadIdx.x, ty = threadIdx.y;      // 32 x 8
    const int u0 = blockIdx.x * 32, h0 = blockIdx.y * 32;
#pragma unroll
    for (int i = 0; i < 4; ++i)
        tile[ty * 4 + i][tx] = W1[(size_t)(h0 + ty * 4 + i) * U_DIM + u0 + tx];
    __syncthreads();
#pragma unroll
    for (int i = 0; i < 4; ++i)
        W1t[(size_t)(u0 + ty * 4 + i) * H_DIM + h0 + tx] =
            f32_to_bf16_rne(tile[tx][ty * 4 + i]);
}

// ---------------- query v2: split-H partial sums + atomics ----------------
__global__ __launch_bounds__(128)
void query_kernel_v2(const float* __restrict__ hidden_t,
                     const float* __restrict__ W2,
                     const float* __restrict__ b1,
                     const float* __restrict__ b2,
                     float* __restrict__ query) {
    const int b  = blockIdx.z;
    const int hc = blockIdx.y;                 // 8 chunks of 128 h
    const int u  = blockIdx.x * 128 + threadIdx.x;
    const float* ht = hidden_t + b * H_DIM + hc * 128;
    const float* w  = W2 + (size_t)hc * 128 * U_DIM + u;
    float acc = (hc == 0) ? (b1[u] + b2[u]) : 0.f;
#pragma unroll 8
    for (int h = 0; h < 128; ++h)
        acc = fmaf(ht[h], w[(size_t)h * U_DIM], acc);
    atomicAdd(&query[b * U_DIM + u], acc);
}

// ---------------- epilogue: tanh(c+q)·V, 16-lane reduce, atomic ----------------
__device__ __forceinline__ void score_epilogue(const floatx4 acc[4][4],
                                               const float* __restrict__ qrow,
                                               const float* __restrict__ V,
                                               float* __restrict__ scores,
                                               int m0, int n0, int wr, int wc, int q, int r) {
#pragma unroll
    for (int mt = 0; mt < 4; ++mt) {
#pragma unroll
        for (int reg = 0; reg < 4; ++reg) {
            float sum = 0.f;
#pragma unroll
            for (int nt = 0; nt < 4; ++nt) {
                const int c = n0 + wc * 64 + nt * 16 + r;
                float x = acc[mt][nt][reg] + qrow[c];
                x = fminf(fmaxf(x, -15.f), 15.f);
                float e = __expf(2.f * x);
                float t = (e - 1.f) / (e + 1.f);
                sum = fmaf(t, V[c], sum);
            }
            sum += __shfl_xor(sum, 1);
            sum += __shfl_xor(sum, 2);
            sum += __shfl_xor(sum, 4);
            sum += __shfl_xor(sum, 8);
            if (r == 0)
                atomicAdd(&scores[m0 + wr * 64 + mt * 16 + q * 4 + reg], sum);
        }
    }
}

// ---------------- v4: BK=64 + XOR bank swizzle + XCD grid swizzle ----------------
__global__ __launch_bounds__(256)
void keys_score_v4(const unsigned short* __restrict__ hb,
                   const unsigned short* __restrict__ W1t,
                   const float* __restrict__ query,
                   const float* __restrict__ V,
                   float* __restrict__ scores) {
    __shared__ unsigned short As[BM * BK];   // 16 KB
    __shared__ unsigned short Bs[BN * BK];   // 16 KB

    const int tid = threadIdx.x;
    const int w = tid >> 6, l = tid & 63;
    const int q = l >> 4, r = l & 15;
    const int wr = w >> 1, wc = w & 1;

    const int bid = blockIdx.x;
    const int col      = (bid >> 3) & 7;
    const int row_band = ((bid >> 6) << 3) | (bid & 7);
    const int m0 = row_band * BM;
    const int n0 = col * BN;

    const int srow   = l >> 3;                    // 0..7
    const int gchunk = ((l & 7) ^ srow) * 8;      // swizzled global chunk (bf16 elems)

    const unsigned short* gA = hb  + ((size_t)(m0 + w * 8 + srow) << 10) + gchunk;
    const unsigned short* gB = W1t + ((size_t)(n0 + w * 8 + srow) << 10) + gchunk;
    unsigned short* lA = &As[(w * 8) * BK];
    unsigned short* lB = &Bs[(w * 8) * BK];

    floatx4 acc[4][4];
#pragma unroll
    for (int mt = 0; mt < 4; ++mt)
#pragma unroll
        for (int nt = 0; nt < 4; ++nt)
            acc[mt][nt] = (floatx4){0.f, 0.f, 0.f, 0.f};

    const int r7 = r & 7;
    for (int kt = 0; kt < H_DIM / BK; ++kt) {
#pragma unroll
        for (int i = 0; i < 4; ++i) {
            GLD16(gA + ((size_t)(i * 32) << 10), lA + i * 32 * BK);
            GLD16(gB + ((size_t)(i * 32) << 10), lB + i * 32 * BK);
        }
        gA += BK; gB += BK;

        __syncthreads();

#pragma unroll
        for (int kh = 0; kh < 2; ++kh) {
            short8 af[4], bfr[4];
#pragma unroll
            for (int mt = 0; mt < 4; ++mt)
                af[mt] = *(const short8*)
                    &As[(wr * 64 + mt * 16 + r) * BK + (((kh << 2) | q) ^ r7) * 8];
#pragma unroll
            for (int nt = 0; nt < 4; ++nt)
                bfr[nt] = *(const short8*)
                    &Bs[(wc * 64 + nt * 16 + r) * BK + (((kh << 2) | q) ^ r7) * 8];
#pragma unroll
            for (int mt = 0; mt < 4; ++mt)
#pragma unroll
                for (int nt = 0; nt < 4; ++nt)
                    acc[mt][nt] = __builtin_amdgcn_mfma_f32_16x16x32_bf16(
                        af[mt], bfr[nt], acc[mt][nt], 0, 0, 0);
        }

        __syncthreads();
    }

    const float* qrow = query + (m0 >> 11) * U_DIM;
    score_epilogue(acc, qrow, V, scores, m0, n0, wr, wc, q, r);
}

// ---------------- v1 fallback (f32 hiddens staged via VGPR) ----------------
__global__ __launch_bounds__(256)
void keys_score_v1(const float* __restrict__ hiddens,
                   const unsigned short* __restrict__ W1t,
                   const float* __restrict__ query,
                   const float* __restrict__ V,
                   float* __restrict__ scores) {
    __shared__ unsigned short As[BM][40];
    __shared__ unsigned short Bs[BN][40];
    const int tid = threadIdx.x;
    const int lane = tid & 63, wave = tid >> 6;
    const int q = lane >> 4, r = lane & 15;
    const int wr = wave >> 1, wc = wave & 1;
    const int m0 = blockIdx.y * BM, n0 = blockIdx.x * BN;
    const int arow = tid >> 3, achunk = tid & 7;
    const int brow = tid >> 2, bchunk = tid & 3;
    floatx4 acc[4][4];
#pragma unroll
    for (int mt = 0; mt < 4; ++mt)
#pragma unroll
        for (int nt = 0; nt < 4; ++nt)
            acc[mt][nt] = (floatx4){0.f, 0.f, 0.f, 0.f};
    for (int kt = 0; kt < H_DIM / 32; ++kt) {
        const float* ag = hiddens + (size_t)(m0 + arow) * H_DIM + kt * 32 + achunk * 4;
#pragma unroll
        for (int i = 0; i < 4; ++i) {
            float4 f = *(const float4*)(ag + (size_t)i * 32 * H_DIM);
            ushort4 h;
            h.x = f32_to_bf16_rne(f.x); h.y = f32_to_bf16_rne(f.y);
            h.z = f32_to_bf16_rne(f.z); h.w = f32_to_bf16_rne(f.w);
            *(ushort4*)&As[arow + i * 32][achunk * 4] = h;
        }
        const unsigned short* bg = W1t + (size_t)(n0 + brow) * H_DIM + kt * 32 + bchunk * 8;
#pragma unroll
        for (int i = 0; i < 2; ++i)
            *(uint4*)&Bs[brow + i * 64][bchunk * 8] = *(const uint4*)(bg + (size_t)i * 64 * H_DIM);
        __syncthreads();
        short8 af[4], bfr[4];
#pragma unroll
        for (int mt = 0; mt < 4; ++mt)
            af[mt] = *(const short8*)&As[wr * 64 + mt * 16 + r][q * 8];
#pragma unroll
        for (int nt = 0; nt < 4; ++nt)
            bfr[nt] = *(const short8*)&Bs[wc * 64 + nt * 16 + r][q * 8];
#pragma unroll
        for (int mt = 0; mt < 4; ++mt)
#pragma unroll
            for (int nt = 0; nt < 4; ++nt)
                acc[mt][nt] = __builtin_amdgcn_mfma_f32_16x16x32_bf16(
                    af[mt], bfr[nt], acc[mt][nt], 0, 0, 0);
        __syncthreads();
    }
    const float* qrow = query + (m0 >> 11) * U_DIM;
    score_epilogue(acc, qrow, V, scores, m0, n0, wr, wc, q, r);
}

// ---------------- softmax stats: per-batch max and 1/sum ----------------
__global__ __launch_bounds__(256)
void softmax_stats_kernel(const float* __restrict__ scores,
                          float2* __restrict__ stats) {
    const int b = blockIdx.x, tid = threadIdx.x;
    const int wave = tid >> 6, lane = tid & 63;
    const float* src = scores + b * S_LEN;
    float v[8];
    float m = -1e30f;
#pragma unroll
    for (int i = 0; i < 8; ++i) { v[i] = src[tid + i * 256]; m = fmaxf(m, v[i]); }
#pragma unroll
    for (int off = 32; off >= 1; off >>= 1) m = fmaxf(m, __shfl_xor(m, off));
    __shared__ float red[4];
    if (lane == 0) red[wave] = m;
    __syncthreads();
    m = fmaxf(fmaxf(red[0], red[1]), fmaxf(red[2], red[3]));
    __syncthreads();
    float s = 0.f;
#pragma unroll
    for (int i = 0; i < 8; ++i) s += __expf(v[i] - m);
#pragma unroll
    for (int off = 32; off >= 1; off >>= 1) s += __shfl_xor(s, off);
    if (lane == 0) red[wave] = s;
    __syncthreads();
    if (tid == 0) {
        s = red[0] + red[1] + red[2] + red[3];
        stats[b] = make_float2(m, 1.f / s);
    }
}

// ---------------- context partial: weights + partial sums, NO atomics ----------------
// block (sc, b): handles 128 s x all 1024 h; writes out_w for its s-range and
// partial[b][sc][h].
__global__ __launch_bounds__(256)
void context_partial_kernel(const float* __restrict__ scores,
                            const float2* __restrict__ stats,
                            const float* __restrict__ hiddens,
                            float* __restrict__ out_w,
                            float* __restrict__ partial) {
    const int b = blockIdx.y, sc = blockIdx.x;  // 16 chunks of 128 s
    const int tid = threadIdx.x;
    __shared__ float wsm[128];

    const float2 st = stats[b];
    if (tid < 128) {
        const int s = sc * 128 + tid;
        const float w = __expf(scores[b * S_LEN + s] - st.x) * st.y;
        wsm[tid] = w;
        out_w[b * S_LEN + s] = w;
    }
    __syncthreads();

    const float* hbase = hiddens + ((size_t)b * S_LEN + sc * 128) * H_DIM + tid * 4;
    float4 acc = make_float4(0.f, 0.f, 0.f, 0.f);
#pragma unroll 4
    for (int s = 0; s < 128; ++s) {
        const float w = wsm[s];
        float4 hv = *(const float4*)(hbase + (size_t)s * H_DIM);
        acc.x = fmaf(w, hv.x, acc.x);
        acc.y = fmaf(w, hv.y, acc.y);
        acc.z = fmaf(w, hv.z, acc.z);
        acc.w = fmaf(w, hv.w, acc.w);
    }
    *(float4*)(partial + ((size_t)(b * 16 + sc) << 10) + tid * 4) = acc;
}

// ---------------- context reduce: sum 16 partials per batch ----------------
__global__ __launch_bounds__(256)
void context_reduce_kernel(const float* __restrict__ partial,
                           float* __restrict__ out_ctx) {
    const int b = blockIdx.x, tid = threadIdx.x;
    float4 acc = make_float4(0.f, 0.f, 0.f, 0.f);
#pragma unroll
    for (int sc = 0; sc < 16; ++sc) {
        float4 p = *(const float4*)(partial + ((size_t)(b * 16 + sc) << 10) + tid * 4);
        acc.x += p.x; acc.y += p.y; acc.z += p.z; acc.w += p.w;
    }
    *(float4*)(out_ctx + b * H_DIM + tid * 4) = acc;
}

extern "C" void kernel_launch(void* const* d_in, const int* in_sizes, int n_in,
                              void* d_out, int out_size, void* d_ws, size_t ws_size,
                              hipStream_t stream) {
    const float* hidden_t = (const float*)d_in[0];
    const float* hiddens  = (const float*)d_in[1];
    const float* W1       = (const float*)d_in[2];
    const float* b1       = (const float*)d_in[3];
    const float* W2       = (const float*)d_in[4];
    const float* b2       = (const float*)d_in[5];
    const float* V        = (const float*)d_in[6];
    // d_in[7] = bV: softmax-invariant, unused.

    float* out_ctx = (float*)d_out;                  // [32,1024]
    float* out_w   = (float*)d_out + B_SZ * H_DIM;   // [32,2048,1]

    char* ws = (char*)d_ws;
    unsigned short* W1t = (unsigned short*)ws;                        // 2 MiB @ 0
    float*  query   = (float*)(ws + (2u << 20));                      // 128 KiB
    float*  scores  = query + B_SZ * U_DIM;                           // 256 KiB
    float2* stats   = (float2*)(scores + B_SZ * S_LEN);               // 256 B
    float*  partial = (float*)(ws + (3u << 20));                      // 2 MiB @ 3 MiB
    unsigned short* hb = (unsigned short*)(ws + (6u << 20));          // 128 MiB @ 6 MiB
    const size_t need = (6u << 20) + (size_t)B_SZ * S_LEN * H_DIM * 2;

    hipMemsetAsync(query,  0, (size_t)B_SZ * U_DIM * sizeof(float), stream);
    hipMemsetAsync(scores, 0, (size_t)B_SZ * S_LEN * sizeof(float), stream);

    transpose_cast_w1<<<dim3(32, 32), dim3(32, 8), 0, stream>>>(W1, W1t);
    query_kernel_v2<<<dim3(8, 8, B_SZ), 128, 0, stream>>>(hidden_t, W2, b1, b2, query);

    if (ws_size >= need) {
        cast_hiddens_kernel<<<32768, 256, 0, stream>>>(hiddens, hb);
        keys_score_v4<<<(U_DIM / BN) * ((B_SZ * S_LEN) / BM), 256, 0, stream>>>(
            hb, W1t, query, V, scores);
    } else {
        keys_score_v1<<<dim3(U_DIM / 128, (B_SZ * S_LEN) / BM), 256, 0, stream>>>(
            hiddens, W1t, query, V, scores);
    }

    softmax_stats_kernel<<<B_SZ, 256, 0, stream>>>(scores, stats);
    context_partial_kernel<<<dim3(16, B_SZ), 256, 0, stream>>>(
        scores, stats, hiddens, out_w, partial);
    context_reduce_kernel<<<B_SZ, 256, 0, stream>>>(partial, out_ctx);
}